// Round 1
// 128.314 us; speedup vs baseline: 1.0397x; 1.0397x over previous
//
#include <hip/hip_runtime.h>
#include <math.h>

// ---------------------------------------------------------------------------
// LatentReverb: B=2, C=4, H=64, W=64.
// k1 (reverb): column-slab redundant halo, lanes = rows. 128 blocks = 2 batch
//   x 64 SINGLE-col slabs x 1024 thr (16 waves). fb_w transposed in LDS (WL).
//   17-col LDS window.  [unchanged — verified]
// k2 (attn+final, fused): 256 blocks = 2 batch x 64 rows x 2 half-rows,
//   512 thr. ALL 4 heads' K/V (4096 keys) staged in 132 KB LDS, chunk-padded
//   (stride 258 float2 -> 8 chunk addrs hit banks 0,4..28, conflict-free
//   b128 broadcast reads). Wave=(head,key-half), lane=(px-group,key-chunk):
//   4 queries x 256 keys/lane -> 32 VALU per ds_read. No key-split => no
//   PN/PD/PM partials, no merge kernel. Softmax bound: kmax/kmin sign trick
//   (args <= 0), exact same formulation as the verified split kernel.
//   Epilogue in-block: out_proj + conv3x3(x) + oc-1x1 + 0.7x+0.3a.
// ---------------------------------------------------------------------------

#define ZERO4 make_float4(0.f, 0.f, 0.f, 0.f)

__device__ __forceinline__ float sigf(float v) { return 1.0f / (1.0f + __expf(-v)); }

// lane i <- lane i-1, lane 0 <- 0   [wave_shr:1]  == value at row r-1
__device__ __forceinline__ float dppL(float v) {
    return __int_as_float(__builtin_amdgcn_mov_dpp(__float_as_int(v), 0x138, 0xf, 0xf, true));
}
// lane i <- lane i+1, lane 63 <- 0  [wave_shl:1]  == value at row r+1
__device__ __forceinline__ float dppR(float v) {
    return __int_as_float(__builtin_amdgcn_mov_dpp(__float_as_int(v), 0x130, 0xf, 0xf, true));
}
__device__ __forceinline__ float4 shL4(float4 v) {   // row r-1 (zero at r=0)
    return make_float4(dppL(v.x), dppL(v.y), dppL(v.z), dppL(v.w));
}
__device__ __forceinline__ float4 shR4(float4 v) {   // row r+1 (zero at r=63)
    return make_float4(dppR(v.x), dppR(v.y), dppR(v.z), dppR(v.w));
}

// one 3x3 tap for all 4 oc x 4 ic, weights from LDS (transposed layout)
__device__ __forceinline__ void tapL(float4& a, const float4 t, const float4* w) {
    const float4 w0 = w[0], w1 = w[1], w2 = w[2], w3 = w[3];
    a.x += w0.x * t.x + w1.x * t.y + w2.x * t.z + w3.x * t.w;
    a.y += w0.y * t.x + w1.y * t.y + w2.y * t.z + w3.y * t.w;
    a.z += w0.z * t.x + w1.z * t.y + w2.z * t.z + w3.z * t.w;
    a.w += w0.w * t.x + w1.w * t.y + w2.w * t.z + w3.w * t.w;
}

__global__ __launch_bounds__(1024, 1) void reverb_qkv_kernel(
    const float* __restrict__ x,
    const float* __restrict__ refl_w,
    const float* __restrict__ refl_d,
    const float* __restrict__ fb_w,
    const float* __restrict__ fb_b,
    const float* __restrict__ d1_w,
    const float* __restrict__ d1_b,
    const float* __restrict__ d2_w,
    const float* __restrict__ d2_b,
    const float* __restrict__ ipw,
    const float* __restrict__ ipb,
    float* __restrict__ Qg, float* __restrict__ Kg, float* __restrict__ Vg)
{
    __shared__ float4 P [17 * 64];    // fb plane, local col-major: P[lc][row]
    __shared__ float4 BL[17 * 64];    // blurred plane
    __shared__ float4 WT[64];         // wet for the owned col
    __shared__ float  GT[3][8];       // gaussian tables
    __shared__ float  WL[9 * 16];     // fb_w transposed: WL[tap][ic][oc]

    const int blk   = blockIdx.x;        // 128 blocks
    const int batch = blk >> 6;          // 0..1
    const int c0    = blk & 63;          // owned column
    const int LB    = c0 - 8;            // global col of local col 0
    const int tid   = threadIdx.x;
    const int wy    = tid >> 6;          // wave 0..15
    const int r     = tid & 63;          // lane == row

    // Gaussian tables (fp64, matches numpy K_TABLE after f32 rounding).
    if (tid < 3) {
        const int rr = tid + 1;
        const int ks = 2 * rr + 1;
        const int s  = (7 - ks) >> 1;
        const double step = 4.0 / (double)(ks - 1);
        double g[7]; double sum = 0.0;
        for (int t = 0; t < 7; ++t) {
            if (t < ks) { double u = -2.0 + step * (double)t; g[t] = exp(-u * u); sum += g[t]; }
        }
        for (int t = 0; t < 7; ++t) GT[tid][t] = 0.0f;
        for (int t = 0; t < ks; ++t) GT[tid][s + t] = (float)(g[t] / sum);
    }
    // transpose fb_w[oc][ic][tap] -> WL[tap*16 + ic*4 + oc]
    if (tid >= 64 && tid < 64 + 144) {
        const int idx = tid - 64;
        const int oc  = idx / 36;
        const int rem = idx - oc * 36;
        const int ic  = rem / 9;
        const int tp  = rem - ic * 9;
        WL[tp * 16 + ic * 4 + oc] = fb_w[idx];
    }

    // stage fb0 = 0.1*x, transposed into col-major local plane (zeros outside)
    for (int idx = tid; idx < 17 * 64; idx += 1024) {
        const int lc  = idx >> 6;
        const int row = idx & 63;
        const int gc  = LB + lc;
        float4 v = ZERO4;
        if (gc >= 0 && gc < 64) {
            const int base = batch * 16384 + row * 64 + gc;
            v.x = 0.1f * x[base];
            v.y = 0.1f * x[base + 4096];
            v.z = 0.1f * x[base + 8192];
            v.w = 0.1f * x[base + 12288];
        }
        P[idx] = v;
    }
    __syncthreads();

    const float4* WL4 = (const float4*)WL;    // WL4[tap*4 + ic]

    double w8 = 1.0;
    for (int j = 0; j < 8; ++j) {
        int kidx = (int)floorf(refl_d[j] * 0.5f);
        kidx = kidx < 0 ? 0 : (kidx > 3 ? 3 : kidx);
        float kv[7];
        #pragma unroll
        for (int u = 0; u < 7; ++u) {
            const float dv = (u == 3) ? 1.0f : 0.0f;
            kv[u] = (kidx == 0) ? dv : GT[kidx - 1][u];
        }
        const float wgt = sigf(refl_w[j]) * (float)w8;

        const int rad = 7 - j;
        const int clo = max(0, c0 - rad);
        const int chi = min(64, c0 + 1 + rad);       // conv cols [clo, chi)

        // ---- blur phase: cols [clo-1, chi] (nBlur <= 17) ----
        const int lcA   = (clo - 1) - LB;            // >= 0
        const int nBlur = (chi + 1) - (clo - 1);
        for (int t = wy; t < nBlur; t += 16) {
            const int lc = lcA + t;
            const int gc = LB + lc;
            float4 b = ZERO4;
            if (gc >= 0 && gc < 64) {
                const float4 v  = P[lc * 64 + r];
                const float4 l1 = shL4(v),  l2 = shL4(l1), l3 = shL4(l2);
                const float4 r1 = shR4(v),  r2 = shR4(r1), r3 = shR4(r2);
                b.x = kv[0]*l3.x + kv[1]*l2.x + kv[2]*l1.x + kv[3]*v.x
                    + kv[4]*r1.x + kv[5]*r2.x + kv[6]*r3.x;
                b.y = kv[0]*l3.y + kv[1]*l2.y + kv[2]*l1.y + kv[3]*v.y
                    + kv[4]*r1.y + kv[5]*r2.y + kv[6]*r3.y;
                b.z = kv[0]*l3.z + kv[1]*l2.z + kv[2]*l1.z + kv[3]*v.z
                    + kv[4]*r1.z + kv[5]*r2.z + kv[6]*r3.z;
                b.w = kv[0]*l3.w + kv[1]*l2.w + kv[2]*l1.w + kv[3]*v.w
                    + kv[4]*r1.w + kv[5]*r2.w + kv[6]*r3.w;
            }
            BL[lc * 64 + r] = b;
        }
        __syncthreads();

        // ---- conv+MLP phase: <=1 col per wave (chi-clo <= 15) ----
        const int c = clo + wy;
        if (wy < chi - clo) {                    // wave-uniform
            const int lc = c - LB;               // 1..15
            const float4 bm = BL[(lc - 1) * 64 + r];
            const float4 bc = BL[lc * 64 + r];
            const float4 bp = BL[(lc + 1) * 64 + r];

            float4 acc = make_float4(fb_b[0], fb_b[1], fb_b[2], fb_b[3]);
            tapL(acc, shL4(bm), WL4 + 0*4);  tapL(acc, shL4(bc), WL4 + 1*4);  tapL(acc, shL4(bp), WL4 + 2*4);
            tapL(acc, bm,       WL4 + 3*4);  tapL(acc, bc,       WL4 + 4*4);  tapL(acc, bp,       WL4 + 5*4);
            tapL(acc, shR4(bm), WL4 + 6*4);  tapL(acc, shR4(bc), WL4 + 7*4);  tapL(acc, shR4(bp), WL4 + 8*4);

            // damp MLP
            float4 rr = acc;
            float h0 = d1_b[0] + d1_w[0]*rr.x + d1_w[1]*rr.y + d1_w[2]*rr.z + d1_w[3]*rr.w;
            float h1 = d1_b[1] + d1_w[4]*rr.x + d1_w[5]*rr.y + d1_w[6]*rr.z + d1_w[7]*rr.w;
            h0 = h0 * sigf(h0);
            h1 = h1 * sigf(h1);
            const float d0  = sigf(d2_b[0] + d2_w[0]*h0 + d2_w[1]*h1);
            const float d1v = sigf(d2_b[1] + d2_w[2]*h0 + d2_w[3]*h1);
            const float d2v = sigf(d2_b[2] + d2_w[4]*h0 + d2_w[5]*h1);
            const float d3v = sigf(d2_b[3] + d2_w[6]*h0 + d2_w[7]*h1);
            rr.x *= d0; rr.y *= d1v; rr.z *= d2v; rr.w *= d3v;

            // fb update (in place; only this wave touches col lc this phase)
            const float4 oldfb = P[lc * 64 + r];
            P[lc * 64 + r] = make_float4(oldfb.x + 0.04f*rr.x, oldfb.y + 0.04f*rr.y,
                                         oldfb.z + 0.04f*rr.z, oldfb.w + 0.04f*rr.w);

            // wet update for owned col
            if (c == c0) {
                float4 wv = make_float4(wgt*rr.x, wgt*rr.y, wgt*rr.z, wgt*rr.w);
                if (j > 0) {
                    const float4 old = WT[r];
                    wv.x += old.x; wv.y += old.y; wv.z += old.z; wv.w += old.w;
                }
                WT[r] = wv;
            }
        }
        __syncthreads();
        w8 *= 0.8;
    }

    // ---- epilogue: qkv = in_proj(wet) for the owned col ----
    if (tid < 64) {
        const float4 wv = WT[tid];
        #pragma unroll
        for (int h = 0; h < 4; ++h) {
            const float q = ipb[h]
                + ipw[h*4+0]*wv.x + ipw[h*4+1]*wv.y
                + ipw[h*4+2]*wv.z + ipw[h*4+3]*wv.w;
            const float k = ipb[4+h]
                + ipw[(4+h)*4+0]*wv.x + ipw[(4+h)*4+1]*wv.y
                + ipw[(4+h)*4+2]*wv.z + ipw[(4+h)*4+3]*wv.w;
            const float v = ipb[8+h]
                + ipw[(8+h)*4+0]*wv.x + ipw[(8+h)*4+1]*wv.y
                + ipw[(8+h)*4+2]*wv.z + ipw[(8+h)*4+3]*wv.w;
            const int o = (batch * 4 + h) * 4096 + tid * 64 + c0;
            Qg[o] = q; Kg[o] = k; Vg[o] = v;
        }
    }
}

// ---------------------------------------------------------------------------
// Fused attention + epilogue.
// 256 blocks = b(2) x y0(64) x half(2); 512 threads (8 waves).
// LDS: KV[4 heads][16 chunks x (256 keys + 2 pad) float2]  (132096 B)
//   chunk stride 258 float2 = 2064 B -> bank offset 4 per chunk: the 8
//   distinct chunk addresses per wave tile banks 0..31 exactly (b128 spans
//   4 banks each) -> conflict-free broadcast reads.
// Wave w: head = w>>1, key-half kh = w&1 (2048 keys).
// Lane: pxg = lane&7 (4 queries px = pxg*4+t), ks2 = lane>>3 (256-key chunk).
// ---------------------------------------------------------------------------
#define KV_CS 258          // float2 per chunk (256 keys + 1 float4 pad)
#define KV_HS (16 * KV_CS) // float2 per head = 4128

__global__ __launch_bounds__(512, 1) void attn_final_kernel(
    const float* __restrict__ x,
    const float* __restrict__ sc_w, const float* __restrict__ sc_b,
    const float* __restrict__ opw,  const float* __restrict__ opb,
    const float* __restrict__ ocw,  const float* __restrict__ ocb,
    const float* __restrict__ Qg,   const float* __restrict__ Kg,
    const float* __restrict__ Vg,   float* __restrict__ out)
{
    __shared__ float2 KV[4 * KV_HS];     // 132096 B interleaved (k,v)
    __shared__ float  XH[4][3][36];      // x halo rows y0-1..y0+1, cols x0-1..x0+32
    __shared__ float2 PND[4][2][32];     // per (head, key-half, px): (num, den)
    __shared__ float2 KRED[4][2];        // per (head, wave-of-head): (kmax, kmin)
    __shared__ float  OH[32][4];         // attn output per (px, head)
    __shared__ float  W2[32][4];         // out_proj per (px, head)
    __shared__ float  SP[8][32];         // spatial conv per (oc, px)

    const int blk = blockIdx.x;
    const int b   = blk >> 7;
    const int rem = blk & 127;
    const int y0  = rem >> 1;
    const int x0  = (rem & 1) << 5;
    const int tid = threadIdx.x;

    // ---- phase 0: stage KV (+ per-head kmax/kmin) and x halo ----
    {
        const int h = tid >> 7;            // 128 threads per head
        const int i = tid & 127;
        const float* Kp = Kg + (b * 4 + h) * 4096;
        const float* Vp = Vg + (b * 4 + h) * 4096;
        float kmx = -3.0e38f, kmn = 3.0e38f;
        #pragma unroll
        for (int m = 0; m < 32; ++m) {
            const int j  = i + m * 128;    // coalesced across the wave
            const float kk = Kp[j];
            const float vv = Vp[j];
            KV[h * KV_HS + (j >> 8) * KV_CS + (j & 255)] = make_float2(kk, vv);
            kmx = fmaxf(kmx, kk);
            kmn = fminf(kmn, kk);
        }
        #pragma unroll
        for (int off = 32; off > 0; off >>= 1) {
            kmx = fmaxf(kmx, __shfl_xor(kmx, off, 64));
            kmn = fminf(kmn, __shfl_xor(kmn, off, 64));
        }
        if ((tid & 63) == 0) KRED[h][(tid >> 6) & 1] = make_float2(kmx, kmn);
    }
    if (tid < 408) {                       // 4 ic x 3 rows x 34 cols
        const int ic = tid / 102;
        const int r2 = tid - ic * 102;
        const int ry = r2 / 34;
        const int cc = r2 - ry * 34;
        const int gy = y0 + ry - 1;
        const int gx = x0 + cc - 1;
        XH[ic][ry][cc] = (gy >= 0 && gy < 64 && gx >= 0 && gx < 64)
                          ? x[(b * 4 + ic) * 4096 + gy * 64 + gx] : 0.0f;
    }
    __syncthreads();

    // ---- attention main loop ----
    {
        const int wv   = tid >> 6;
        const int lane = tid & 63;
        const int h    = wv >> 1;
        const int kh   = wv & 1;
        const int pxg  = lane & 7;
        const int ks2  = lane >> 3;

        const float2 kr0 = KRED[h][0], kr1 = KRED[h][1];
        const float kmax = fmaxf(kr0.x, kr1.x);
        const float kmin = fminf(kr0.y, kr1.y);

        const float L2E = 1.4426950408889634f;
        const float4 qv = *(const float4*)(Qg + (b * 4 + h) * 4096
                                           + y0 * 64 + x0 + pxg * 4);
        float q2[4], nm2[4];
        {
            const float qs[4] = {qv.x, qv.y, qv.z, qv.w};
            #pragma unroll
            for (int t = 0; t < 4; ++t) {
                q2[t]  = qs[t] * L2E;
                nm2[t] = -(((qs[t] >= 0.0f) ? qs[t] * kmax : qs[t] * kmin) * L2E);
            }
        }

        const int c0 = kh * 8 + ks2;                       // chunk 0..15
        const float4* KV4 = (const float4*)(KV + h * KV_HS + c0 * KV_CS);

        float num[4] = {0.f, 0.f, 0.f, 0.f};
        float den[4] = {0.f, 0.f, 0.f, 0.f};
        #pragma unroll 8
        for (int jj = 0; jj < 128; ++jj) {
            const float4 f = KV4[jj];                      // (k0,v0,k1,v1) broadcast
            #pragma unroll
            for (int t = 0; t < 4; ++t) {
                const float e0 = __builtin_amdgcn_exp2f(__fmaf_rn(q2[t], f.x, nm2[t]));
                den[t] += e0;  num[t] = __fmaf_rn(e0, f.y, num[t]);
                const float e1 = __builtin_amdgcn_exp2f(__fmaf_rn(q2[t], f.z, nm2[t]));
                den[t] += e1;  num[t] = __fmaf_rn(e1, f.w, num[t]);
            }
        }
        // reduce over ks2 (lane bits 3..5)
        #pragma unroll
        for (int off = 8; off <= 32; off <<= 1) {
            #pragma unroll
            for (int t = 0; t < 4; ++t) {
                num[t] += __shfl_xor(num[t], off, 64);
                den[t] += __shfl_xor(den[t], off, 64);
            }
        }
        if (ks2 == 0) {
            #pragma unroll
            for (int t = 0; t < 4; ++t)
                PND[h][kh][pxg * 4 + t] = make_float2(num[t], den[t]);
        }
    }
    __syncthreads();

    // ---- merge halves -> attn output ----
    if (tid < 128) {
        const int px = tid & 31, hh = tid >> 5;
        const float2 a = PND[hh][0][px], c = PND[hh][1][px];
        OH[px][hh] = (a.x + c.x) / (a.y + c.y);
    }
    __syncthreads();

    // ---- spatial conv (threads 0..255) and out_proj (threads 256..383) ----
    if (tid < 256) {
        const int px = tid & 31, oc = tid >> 5;
        float a = sc_b[oc];
        #pragma unroll
        for (int ic = 0; ic < 4; ++ic)
            #pragma unroll
            for (int ky = 0; ky < 3; ++ky)
                #pragma unroll
                for (int kx = 0; kx < 3; ++kx)
                    a += sc_w[(oc * 4 + ic) * 9 + ky * 3 + kx] * XH[ic][ky][px + kx];
        SP[oc][px] = a;
    } else if (tid < 384) {
        const int t2 = tid - 256;
        const int px = t2 & 31, hh = t2 >> 5;
        W2[px][hh] = opb[hh]
                   + opw[hh*4+0]*OH[px][0] + opw[hh*4+1]*OH[px][1]
                   + opw[hh*4+2]*OH[px][2] + opw[hh*4+3]*OH[px][3];
    }
    __syncthreads();

    // ---- oc 1x1 + wet mix + store ----
    if (tid < 128) {
        const int px = tid & 31, c = tid >> 5;
        float a = ocb[c];
        #pragma unroll
        for (int j = 0; j < 8; ++j)  a += ocw[c * 12 + j] * SP[j][px];
        #pragma unroll
        for (int hh = 0; hh < 4; ++hh) a += ocw[c * 12 + 8 + hh] * W2[px][hh];
        const int idx = (b * 4 + c) * 4096 + y0 * 64 + x0 + px;
        out[idx] = 0.7f * XH[c][1][px + 1] + 0.3f * a;
    }
}

extern "C" void kernel_launch(void* const* d_in, const int* in_sizes, int n_in,
                              void* d_out, int out_size, void* d_ws, size_t ws_size,
                              hipStream_t stream) {
    const float* x      = (const float*)d_in[0];
    const float* refl_w = (const float*)d_in[1];
    const float* refl_d = (const float*)d_in[2];
    const float* sc_w   = (const float*)d_in[3];
    const float* sc_b   = (const float*)d_in[4];
    const float* fb_w   = (const float*)d_in[5];
    const float* fb_b   = (const float*)d_in[6];
    const float* d1_w   = (const float*)d_in[7];
    const float* d1_b   = (const float*)d_in[8];
    const float* d2_w   = (const float*)d_in[9];
    const float* d2_b   = (const float*)d_in[10];
    const float* ipw    = (const float*)d_in[11];
    const float* ipb    = (const float*)d_in[12];
    const float* opw    = (const float*)d_in[13];
    const float* opb    = (const float*)d_in[14];
    const float* ocw    = (const float*)d_in[15];
    const float* ocb    = (const float*)d_in[16];
    float* out = (float*)d_out;

    // ws: Q | K | V (32768 floats each)
    float* Q = (float*)d_ws;
    float* K = Q + 32768;
    float* V = K + 32768;

    reverb_qkv_kernel<<<dim3(128), dim3(1024), 0, stream>>>(
        x, refl_w, refl_d, fb_w, fb_b, d1_w, d1_b, d2_w, d2_b, ipw, ipb,
        Q, K, V);
    attn_final_kernel<<<dim3(256), dim3(512), 0, stream>>>(
        x, sc_w, sc_b, opw, opb, ocw, ocb, Q, K, V, out);
}